// Round 7
// baseline (294.511 us; speedup 1.0000x reference)
//
#include <hip/hip_runtime.h>

#define DIM 768
#define NHEADS 12
#define HDIM 64
#define BATCH 2
#define SEQ 2048
#define ROWS (BATCH*SEQ)   // 4096
#define KSPLIT 4

typedef __attribute__((ext_vector_type(8))) _Float16 f16x8;
typedef __attribute__((ext_vector_type(4))) _Float16 f16x4;
typedef __attribute__((ext_vector_type(2))) _Float16 f16x2;
typedef __attribute__((ext_vector_type(4))) float    f32x4;

// async global->LDS DMA, 16 B per lane; LDS dest must be wave-uniform base
__device__ __forceinline__ void dma16(const _Float16* g, _Float16* l) {
    __builtin_amdgcn_global_load_lds(
        (const __attribute__((address_space(1))) unsigned int*)g,
        (__attribute__((address_space(3))) unsigned int*)l, 16, 0, 0);
}

// ============================================================
// Fragment layout F(mt, kt): 16 rows x 32 cols of row-major M[R][C]:
//   frag[lane][j] = M[mt*16 + (lane&15)][kt*32 + (lane>>4)*8 + j]
// stored at dst[((mt*(C/32) + kt)*64 + lane)*8] (halves).
// V tile layout (for 16x16x16 PV MFMA): per 16-key chunk kc,
//   Vkt[((kc*48 + (h*4+dt))*64 + lane)*4] : tile[lane][j] =
//   V[d = (h*4+dt)*16 + (lane&15)][key = kc*16 + (lane>>4)*4 + j]
// ============================================================

// ---- all 4 fp32->f16 frag conversions in one launch (all have C=768) ----
__global__ __launch_bounds__(256) void cvt_all(
    const float* __restrict__ x,  const float* __restrict__ wq,
    const float* __restrict__ wk, const float* __restrict__ wv,
    _Float16* __restrict__ xf,  _Float16* __restrict__ wqf,
    _Float16* __restrict__ wkf, _Float16* __restrict__ wvf)
{
    const int lane = threadIdx.x & 63;
    const int wid  = (blockIdx.x * 256 + threadIdx.x) >> 6;
    const float* src; _Float16* dst; int t;
    if (wid < 6144)      { src = x;  dst = xf;  t = wid;        }
    else if (wid < 7296) { src = wq; dst = wqf; t = wid - 6144; }
    else if (wid < 8448) { src = wk; dst = wkf; t = wid - 7296; }
    else                 { src = wv; dst = wvf; t = wid - 8448; }
    const int c = lane & 15, quad = lane >> 4;
    const int mt = t / 24, kt = t % 24;
    const float* p = src + (size_t)(mt*16 + c) * 768 + kt*32 + quad*8;
    float4 v0 = *(const float4*)p;
    float4 v1 = *(const float4*)(p + 4);
    f16x8 o;
    o[0]=(_Float16)v0.x; o[1]=(_Float16)v0.y; o[2]=(_Float16)v0.z; o[3]=(_Float16)v0.w;
    o[4]=(_Float16)v1.x; o[5]=(_Float16)v1.y; o[6]=(_Float16)v1.z; o[7]=(_Float16)v1.w;
    *reinterpret_cast<f16x8*>(dst + ((size_t)t * 64 + lane) * 8) = o;
}

// ---- all 3 projections: 128x128 tiles, global_load_lds staging ----
// bid < 384: C = x * [Wq;Wk]^T  (M=4096, N=1536) -> Qf/Kf frag layout
// bid >= 384: C = Wv * x^T      (M=768, N=4096)  -> Vkt 16x16 tile layout
__global__ __launch_bounds__(256) void gemm3(
    const _Float16* __restrict__ xf, const _Float16* __restrict__ wqkf,
    const _Float16* __restrict__ wvf,
    _Float16* __restrict__ Qf, _Float16* __restrict__ Kf, _Float16* __restrict__ Vkt)
{
    __shared__ _Float16 Ab[2][8*512];
    __shared__ _Float16 Bb[2][8*512];
    const int tid = threadIdx.x, lane = tid & 63, w = tid >> 6;
    const int c = lane & 15, quad = lane >> 4;

    const _Float16 *Af, *Bf;
    int mt0, nt0, mode;
    if ((int)blockIdx.x < 384) {
        int mt = blockIdx.x / 12, nt = blockIdx.x % 12;
        Af = xf; Bf = wqkf; mt0 = mt*8; nt0 = nt*8; mode = 0;
    } else {
        int v = blockIdx.x - 384;
        int mt = v / 32, nt = v % 32;
        Af = wvf; Bf = xf; mt0 = mt*8; nt0 = nt*8; mode = 1;
    }

    auto stage = [&](int kt, int buf) {
#pragma unroll
        for (int u = 0; u < 4; ++u) {
            const int cc = w*4 + u;
            const _Float16* s = (cc < 8) ? Af + ((size_t)(mt0+cc)*24 + kt)*512
                                         : Bf + ((size_t)(nt0+cc-8)*24 + kt)*512;
            _Float16* d = (cc < 8) ? &Ab[buf][cc*512] : &Bb[buf][(cc-8)*512];
            dma16(s + lane*8, d);
        }
    };

    stage(0, 0);
    __syncthreads();

    f32x4 acc[4][4] = {};
    for (int kt = 0; kt < 24; ++kt) {
        const int cur = kt & 1;
        if (kt < 23) stage(kt+1, cur^1);
        f16x8 a[4], b[4];
#pragma unroll
        for (int i = 0; i < 4; ++i)
            a[i] = *(const f16x8*)(&Ab[cur][((w>>1)*4 + i)*512] + lane*8);
#pragma unroll
        for (int j = 0; j < 4; ++j)
            b[j] = *(const f16x8*)(&Bb[cur][((w&1)*4 + j)*512] + lane*8);
#pragma unroll
        for (int i = 0; i < 4; ++i)
#pragma unroll
            for (int j = 0; j < 4; ++j)
                acc[i][j] = __builtin_amdgcn_mfma_f32_16x16x32_f16(a[i], b[j], acc[i][j], 0,0,0);
        __syncthreads();
    }

    // epilogue: per-wave 32x32 transposes (buffers dead after last barrier)
    _Float16* L = &Ab[0][0] + w*1280;   // 32x40 halves per wave
#pragma unroll
    for (int i2 = 0; i2 < 2; ++i2)
#pragma unroll
        for (int j2 = 0; j2 < 2; ++j2) {
#pragma unroll
            for (int ii = 0; ii < 2; ++ii)
#pragma unroll
                for (int jj = 0; jj < 2; ++jj)
#pragma unroll
                    for (int r = 0; r < 4; ++r)
                        L[(ii*16 + quad*4 + r)*40 + jj*16 + c] =
                            (_Float16)acc[i2*2+ii][j2*2+jj][r];
#pragma unroll
            for (int ii = 0; ii < 2; ++ii) {
                const int mtg = mt0 + (w>>1)*4 + i2*2 + ii;   // 16-row unit
                if (mode == 0) {
                    f16x8 v = *(const f16x8*)(L + (ii*16 + c)*40 + quad*8);
                    const int nt32 = (nt0 + (w&1)*4)/2 + j2;  // 32-col unit
                    _Float16* dst = (nt32 < 24)
                        ? Qf + ((size_t)(mtg*24 + nt32)*64 + lane)*8
                        : Kf + ((size_t)(mtg*24 + nt32 - 24)*64 + lane)*8;
                    *(f16x8*)dst = v;
                } else {
#pragma unroll
                    for (int jj = 0; jj < 2; ++jj) {
                        f16x4 v4 = *(const f16x4*)(L + (ii*16 + c)*40 + jj*16 + quad*4);
                        const int kcu = nt0 + (w&1)*4 + j2*2 + jj;   // 16-key unit
                        *(f16x4*)(Vkt + ((size_t)kcu*48 + mtg)*256 + lane*4) = v4;
                    }
                }
            }
        }
}

// ---- fused attention: K AND V via DMA double-buffer, 16-key subtiles ----
// grid: 2b x 4ks x 32qb = 256 blocks, 512 thr (8 waves), 1 block/CU.
// Block = 64 q-rows (4 qt) x 512 keys; 32 subtiles of 16 keys.
// wave w: qi = w>>1 (q-tile), g = w&1 (head-group in ph1, d-half in ph2).
// ph1: 6 heads x 16 keys, f16x2 score exchange (partner r's only, no dup);
// softmax: no max-subtract (|s|<~55, f32-safe), r-split, tree sum;
// ph2 (pipelined one subtile behind): 12 heads x 2 d-tiles, 16x16x16 MFMA.
__global__ __launch_bounds__(512) __attribute__((amdgpu_waves_per_eu(2, 2)))
void attn_kernel(
    const _Float16* __restrict__ Qf, const _Float16* __restrict__ Kf,
    const _Float16* __restrict__ Vkt,
    float* __restrict__ out,          // ks==0 partial (covers all elements)
    _Float16* __restrict__ part)      // [3][4096][768] f16, ks=1..3
{
    __shared__ _Float16 Kb[2][24*512];    // 48 KB
    __shared__ _Float16 Vb[2][24*512];    // 48 KB
    __shared__ _Float16 Pl[4*12*16*24];   // 36 KB  (16 keys + 8 pad)
    __shared__ f16x2    Sl[4*12*64];      // 12 KB  score exchange
    const int tid = threadIdx.x, lane = tid & 63, w = tid >> 6;
    const int c = lane & 15, quad = lane >> 4;
    const int qi = w >> 1, g = w & 1;

    const int bid = blockIdx.x;
    const int qb = bid & 31;
    const int ks = (bid >> 5) & 3;
    const int b  = bid >> 7;
    const int qrow0 = b*SEQ + qb*64;
    const int qt16  = (qrow0 >> 4) + qi;
    const int kb16  = (b*SEQ + ks*(SEQ/KSPLIT)) >> 4;

    // Q frags: q-tile qi, heads g*6..g*6+5 (48 VGPRs)
    f16x8 qreg[12];
#pragma unroll
    for (int u = 0; u < 12; ++u)
        qreg[u] = *(const f16x8*)(Qf + ((size_t)(qt16*24 + g*12 + u)*64 + lane)*8);

    // preamble: DMA subtile 0 (K 24 frags + V 24 tile-pairs, 3 each/wave)
#pragma unroll
    for (int u = 0; u < 3; ++u)
        dma16(Kf + ((size_t)kb16*24 + w*3 + u)*512 + lane*8, &Kb[0][(w*3+u)*512]);
#pragma unroll
    for (int u = 0; u < 3; ++u)
        dma16(Vkt + (size_t)kb16*12288 + (w*3+u)*512 + lane*8, &Vb[0][(w*3+u)*512]);
    __syncthreads();

    f32x4 o_acc[12][2] = {};   // 96 VGPRs

    auto ph2 = [&](int vbuf) {
#pragma unroll
        for (int h = 0; h < 12; ++h) {
            f16x4 pf = *(const f16x4*)(Pl + ((qi*12 + h)*16 + c)*24 + quad*4);
#pragma unroll
            for (int dd = 0; dd < 2; ++dd) {
                f16x4 vv = *(const f16x4*)(&Vb[vbuf][(h*4 + g*2 + dd)*256] + lane*4);
                o_acc[h][dd] = __builtin_amdgcn_mfma_f32_16x16x16f16(pf, vv, o_acc[h][dd], 0,0,0);
            }
        }
    };

    for (int t = 0; t < 32; ++t) {
        const int cur = t & 1, nxt = cur ^ 1;
        // K-DMA for subtile t+1 (buffer free since barrier A(t-1))
        if (t < 31) {
#pragma unroll
            for (int u = 0; u < 3; ++u)
                dma16(Kf + ((size_t)(kb16+t+1)*24 + w*3 + u)*512 + lane*8,
                      &Kb[nxt][(w*3+u)*512]);
        }
        // ph2 of subtile t-1 (V lives in buffer (t-1)&1 == nxt)
        if (t > 0) ph2(nxt);
        // ---- ph1: 6 heads x 16 keys ----
        f32x4 s6[6];
#pragma unroll
        for (int hh = 0; hh < 6; ++hh) {
            f16x8 ka = *(const f16x8*)(&Kb[cur][(g*12 + hh*2    )*512] + lane*8);
            f16x8 k2 = *(const f16x8*)(&Kb[cur][(g*12 + hh*2 + 1)*512] + lane*8);
            f32x4 a = {};
            a = __builtin_amdgcn_mfma_f32_16x16x32_f16(qreg[hh*2],   ka, a, 0,0,0);
            a = __builtin_amdgcn_mfma_f32_16x16x32_f16(qreg[hh*2+1], k2, a, 0,0,0);
            s6[hh] = a;   // S[q=quad*4+r][k=c]
        }
        // exchange partner's two r-values (f16x2, one b32/head)
        const int pr = 2*(1-g);
#pragma unroll
        for (int hh = 0; hh < 6; ++hh) {
            f16x2 sv; sv[0] = (_Float16)s6[hh][pr]; sv[1] = (_Float16)s6[hh][pr+1];
            Sl[(qi*12 + g*6 + hh)*64 + lane] = sv;
        }
        __syncthreads();   // A
        // V-DMA for subtile t+1 (buffer nxt freed by barrier A)
        if (t < 31) {
#pragma unroll
            for (int u = 0; u < 3; ++u)
                dma16(Vkt + (size_t)(kb16+t+1)*12288 + (w*3+u)*512 + lane*8,
                      &Vb[nxt][(w*3+u)*512]);
        }
        // ---- softmax: own 2 r's, all 12 heads, each (q,k,h) exactly once ----
        f16x2 sp[6];
#pragma unroll
        for (int hh = 0; hh < 6; ++hh)
            sp[hh] = Sl[(qi*12 + (1-g)*6 + hh)*64 + lane];
#pragma unroll
        for (int rr = 0; rr < 2; ++rr) {
            const int r = 2*g + rr;
            float e[12];
#pragma unroll
            for (int hh = 0; hh < 6; ++hh) {
                e[g*6 + hh]     = __expf(s6[hh][r]);
                e[(1-g)*6 + hh] = __expf((float)sp[hh][rr]);
            }
            float s01 = e[0]+e[1], s23 = e[2]+e[3], s45 = e[4]+e[5];
            float s67 = e[6]+e[7], s89 = e[8]+e[9], sab = e[10]+e[11];
            float sum = ((s01+s23)+(s45+s67)) + (s89+sab);
            const float inv = 1.0f / (sum * 27.712812921102035f);   // /sqrt(768)
#pragma unroll
            for (int h = 0; h < 12; ++h)
                Pl[((qi*12 + h)*16 + quad*4 + r)*24 + c] = (_Float16)(e[h]*inv);
        }
        __syncthreads();   // B (also drains the t+1 DMAs)
    }
    ph2(1);   // subtile 31 (V in buffer 1)

    // ---- epilogue ----
    if (ks == 0) {
#pragma unroll
        for (int h = 0; h < 12; ++h)
#pragma unroll
            for (int dd = 0; dd < 2; ++dd) {
                const int col = h*64 + (g*2 + dd)*16 + c;
#pragma unroll
                for (int r = 0; r < 4; ++r)
                    out[(size_t)(qrow0 + qi*16 + quad*4 + r) * DIM + col] = o_acc[h][dd][r];
            }
    } else {
        _Float16* dst = part + (size_t)(ks - 1) * ROWS * DIM;
#pragma unroll
        for (int h = 0; h < 12; ++h)
#pragma unroll
            for (int dd = 0; dd < 2; ++dd) {
                const int col = h*64 + (g*2 + dd)*16 + c;
#pragma unroll
                for (int r = 0; r < 4; ++r)
                    dst[(size_t)(qrow0 + qi*16 + quad*4 + r) * DIM + col] =
                        (_Float16)o_acc[h][dd][r];
            }
    }
}

// ---- out += sum of 3 f16 partials ----
__global__ __launch_bounds__(256) void reduce_add4(
    float* __restrict__ out, const _Float16* __restrict__ part, int n4)
{
    int i = blockIdx.x * 256 + threadIdx.x;
    if (i >= n4) return;
    float4 o = reinterpret_cast<float4*>(out)[i];
    const size_t N = (size_t)ROWS * DIM;
#pragma unroll
    for (int p = 0; p < 3; ++p) {
        f16x4 v = reinterpret_cast<const f16x4*>(part + p * N)[i];
        o.x += (float)v[0]; o.y += (float)v[1]; o.z += (float)v[2]; o.w += (float)v[3];
    }
    reinterpret_cast<float4*>(out)[i] = o;
}

// ------------------------------- launch ----------------------------------
extern "C" void kernel_launch(void* const* d_in, const int* in_sizes, int n_in,
                              void* d_out, int out_size, void* d_ws, size_t ws_size,
                              hipStream_t stream)
{
    const float* x  = (const float*)d_in[0];
    const float* Wq = (const float*)d_in[1];
    const float* Wk = (const float*)d_in[2];
    const float* Wv = (const float*)d_in[3];

    _Float16* ws  = (_Float16*)d_ws;
    const size_t XS = (size_t)ROWS * DIM;   // 3145728
    const size_t WS = (size_t)DIM * DIM;    // 589824
    _Float16* xf   = ws;
    _Float16* wqf  = xf  + XS;              // wq+wk adjacent = stacked [Wq;Wk]
    _Float16* wkf  = wqf + WS;
    _Float16* wvf  = wkf + WS;
    _Float16* Qf   = wvf + WS;
    _Float16* Kf   = Qf  + XS;
    _Float16* Vkt  = Kf  + XS;
    _Float16* part = Vkt + XS;              // 3 * XS f16 partials

    cvt_all<<<2400, 256, 0, stream>>>(x, Wq, Wk, Wv, xf, wqf, wkf, wvf);
    gemm3<<<576, 256, 0, stream>>>(xf, wqf, wvf, Qf, Kf, Vkt);
    attn_kernel<<<BATCH * KSPLIT * 32, 512, 0, stream>>>(
        Qf, Kf, Vkt, (float*)d_out, part);
    reduce_add4<<<(int)(XS/4 + 255)/256, 256, 0, stream>>>(
        (float*)d_out, part, (int)(XS/4));
}

// Round 8
// 191.896 us; speedup vs baseline: 1.5347x; 1.5347x over previous
//
#include <hip/hip_runtime.h>

#define DIM 768
#define NHEADS 12
#define HDIM 64
#define BATCH 2
#define SEQ 2048
#define ROWS (BATCH*SEQ)   // 4096
#define KSPLIT 4

typedef __attribute__((ext_vector_type(8))) _Float16 f16x8;
typedef __attribute__((ext_vector_type(4))) _Float16 f16x4;
typedef __attribute__((ext_vector_type(2))) _Float16 f16x2;
typedef __attribute__((ext_vector_type(4))) float    f32x4;

// async global->LDS DMA, 16 B per lane; LDS dest must be wave-uniform base
__device__ __forceinline__ void dma16(const _Float16* g, _Float16* l) {
    __builtin_amdgcn_global_load_lds(
        (const __attribute__((address_space(1))) unsigned int*)g,
        (__attribute__((address_space(3))) unsigned int*)l, 16, 0, 0);
}

// ============================================================
// Fragment layout F(mt, kt): 16 rows x 32 cols of row-major M[R][C]:
//   frag[lane][j] = M[mt*16 + (lane&15)][kt*32 + (lane>>4)*8 + j]
// stored at dst[((mt*(C/32) + kt)*64 + lane)*8] (halves).
// V tile layout (for 16x16x16 PV MFMA): per 16-key chunk kc,
//   Vkt[((kc*48 + (h*4+dt))*64 + lane)*4] : tile[lane][j] =
//   V[d = (h*4+dt)*16 + (lane&15)][key = kc*16 + (lane>>4)*4 + j]
// ============================================================

// ---- all 4 fp32->f16 frag conversions in one launch (all have C=768) ----
__global__ __launch_bounds__(256) void cvt_all(
    const float* __restrict__ x,  const float* __restrict__ wq,
    const float* __restrict__ wk, const float* __restrict__ wv,
    _Float16* __restrict__ xf,  _Float16* __restrict__ wqf,
    _Float16* __restrict__ wkf, _Float16* __restrict__ wvf)
{
    const int lane = threadIdx.x & 63;
    const int wid  = (blockIdx.x * 256 + threadIdx.x) >> 6;
    const float* src; _Float16* dst; int t;
    if (wid < 6144)      { src = x;  dst = xf;  t = wid;        }
    else if (wid < 7296) { src = wq; dst = wqf; t = wid - 6144; }
    else if (wid < 8448) { src = wk; dst = wkf; t = wid - 7296; }
    else                 { src = wv; dst = wvf; t = wid - 8448; }
    const int c = lane & 15, quad = lane >> 4;
    const int mt = t / 24, kt = t % 24;
    const float* p = src + (size_t)(mt*16 + c) * 768 + kt*32 + quad*8;
    float4 v0 = *(const float4*)p;
    float4 v1 = *(const float4*)(p + 4);
    f16x8 o;
    o[0]=(_Float16)v0.x; o[1]=(_Float16)v0.y; o[2]=(_Float16)v0.z; o[3]=(_Float16)v0.w;
    o[4]=(_Float16)v1.x; o[5]=(_Float16)v1.y; o[6]=(_Float16)v1.z; o[7]=(_Float16)v1.w;
    *reinterpret_cast<f16x8*>(dst + ((size_t)t * 64 + lane) * 8) = o;
}

// ---- all 3 projections: 128x128 tiles, global_load_lds staging ----
// bid < 384: C = x * [Wq;Wk]^T  (M=4096, N=1536) -> Qf/Kf frag layout
// bid >= 384: C = Wv * x^T      (M=768, N=4096)  -> Vkt 16x16 tile layout
__global__ __launch_bounds__(256) void gemm3(
    const _Float16* __restrict__ xf, const _Float16* __restrict__ wqkf,
    const _Float16* __restrict__ wvf,
    _Float16* __restrict__ Qf, _Float16* __restrict__ Kf, _Float16* __restrict__ Vkt)
{
    __shared__ _Float16 Ab[2][8*512];
    __shared__ _Float16 Bb[2][8*512];
    const int tid = threadIdx.x, lane = tid & 63, w = tid >> 6;
    const int c = lane & 15, quad = lane >> 4;

    const _Float16 *Af, *Bf;
    int mt0, nt0, mode;
    if ((int)blockIdx.x < 384) {
        int mt = blockIdx.x / 12, nt = blockIdx.x % 12;
        Af = xf; Bf = wqkf; mt0 = mt*8; nt0 = nt*8; mode = 0;
    } else {
        int v = blockIdx.x - 384;
        int mt = v / 32, nt = v % 32;
        Af = wvf; Bf = xf; mt0 = mt*8; nt0 = nt*8; mode = 1;
    }

    auto stage = [&](int kt, int buf) {
#pragma unroll
        for (int u = 0; u < 4; ++u) {
            const int cc = w*4 + u;
            const _Float16* s = (cc < 8) ? Af + ((size_t)(mt0+cc)*24 + kt)*512
                                         : Bf + ((size_t)(nt0+cc-8)*24 + kt)*512;
            _Float16* d = (cc < 8) ? &Ab[buf][cc*512] : &Bb[buf][(cc-8)*512];
            dma16(s + lane*8, d);
        }
    };

    stage(0, 0);
    __syncthreads();

    f32x4 acc[4][4] = {};
    for (int kt = 0; kt < 24; ++kt) {
        const int cur = kt & 1;
        if (kt < 23) stage(kt+1, cur^1);
        f16x8 a[4], b[4];
#pragma unroll
        for (int i = 0; i < 4; ++i)
            a[i] = *(const f16x8*)(&Ab[cur][((w>>1)*4 + i)*512] + lane*8);
#pragma unroll
        for (int j = 0; j < 4; ++j)
            b[j] = *(const f16x8*)(&Bb[cur][((w&1)*4 + j)*512] + lane*8);
#pragma unroll
        for (int i = 0; i < 4; ++i)
#pragma unroll
            for (int j = 0; j < 4; ++j)
                acc[i][j] = __builtin_amdgcn_mfma_f32_16x16x32_f16(a[i], b[j], acc[i][j], 0,0,0);
        __syncthreads();
    }

    // epilogue: per-wave 32x32 transposes (buffers dead after last barrier)
    _Float16* L = &Ab[0][0] + w*1280;   // 32x40 halves per wave
#pragma unroll
    for (int i2 = 0; i2 < 2; ++i2)
#pragma unroll
        for (int j2 = 0; j2 < 2; ++j2) {
#pragma unroll
            for (int ii = 0; ii < 2; ++ii)
#pragma unroll
                for (int jj = 0; jj < 2; ++jj)
#pragma unroll
                    for (int r = 0; r < 4; ++r)
                        L[(ii*16 + quad*4 + r)*40 + jj*16 + c] =
                            (_Float16)acc[i2*2+ii][j2*2+jj][r];
#pragma unroll
            for (int ii = 0; ii < 2; ++ii) {
                const int mtg = mt0 + (w>>1)*4 + i2*2 + ii;   // 16-row unit
                if (mode == 0) {
                    f16x8 v = *(const f16x8*)(L + (ii*16 + c)*40 + quad*8);
                    const int nt32 = (nt0 + (w&1)*4)/2 + j2;  // 32-col unit
                    _Float16* dst = (nt32 < 24)
                        ? Qf + ((size_t)(mtg*24 + nt32)*64 + lane)*8
                        : Kf + ((size_t)(mtg*24 + nt32 - 24)*64 + lane)*8;
                    *(f16x8*)dst = v;
                } else {
#pragma unroll
                    for (int jj = 0; jj < 2; ++jj) {
                        f16x4 v4 = *(const f16x4*)(L + (ii*16 + c)*40 + jj*16 + quad*4);
                        const int kcu = nt0 + (w&1)*4 + j2*2 + jj;   // 16-key unit
                        *(f16x4*)(Vkt + ((size_t)kcu*48 + mtg)*256 + lane*4) = v4;
                    }
                }
            }
        }
}

// ---- fused attention: 128-VGPR waves, 2 blocks/CU, 2 barriers/iter ----
// grid: 2b x 4ks x 64qb = 512 blocks (2/CU), 512 thr (8 waves).
// Block = 32 q-rows (2 qt) x 512 keys; 32 subtiles of 16 keys.
// Wave (qi = w>>2, g = w&3):
//   ph1: heads 3g..3g+2 x 16 keys  (qreg 24 + s3 12 VGPRs)
//   softmax: owns r = g (4-way r-split over the q-quad, no duplication)
//   ph2: all 12 heads x d-tile dt = g (o_acc 48 VGPRs), lags one subtile.
// Loop invariant entering iter t: Kb=K(t), Vb=V(t-1), Pl=P(t-1).
//   [ph1(t); raw s->Sr; ph2(t-1)] barrier A [dma V(t),K(t+1); softmax->Pl] barrier B
// Single-buffered K/V: the drain at B is covered by the co-resident block.
__global__ __launch_bounds__(512) __attribute__((amdgpu_waves_per_eu(4)))
void attn_kernel(
    const _Float16* __restrict__ Qf, const _Float16* __restrict__ Kf,
    const _Float16* __restrict__ Vkt,
    float* __restrict__ out,          // ks==0 partial (covers all elements)
    _Float16* __restrict__ part)      // [3][4096][768] f16, ks=1..3
{
    __shared__ _Float16 Kb[24*512];     // 24 KB: K subtile (24 frags)
    __shared__ _Float16 Vb[48*256];     // 24 KB: V subtile (48 16x16 tiles)
    __shared__ _Float16 Sr[2*12*320];   // 15 KB: raw scores, q-row stride 20
    __shared__ _Float16 Pl[2*12*320];   // 15 KB: P, same layout
    const int tid = threadIdx.x, lane = tid & 63, w = tid >> 6;
    const int c = lane & 15, quad = lane >> 4;
    const int qi = w >> 2, g = w & 3;

    const int bid = blockIdx.x;
    const int qb = bid & 63;
    const int ks = (bid >> 6) & 3;
    const int b  = bid >> 8;
    const int qrow0 = b*SEQ + qb*32;
    const int qt16  = (qrow0 >> 4) + qi;
    const int kb16  = (b*SEQ + ks*(SEQ/KSPLIT)) >> 4;

    // Q frags: q-tile qi, heads 3g..3g+2 (24 VGPRs)
    f16x8 qreg[6];
#pragma unroll
    for (int u = 0; u < 6; ++u)
        qreg[u] = *(const f16x8*)(Qf + ((size_t)(qt16*24 + g*6 + u)*64 + lane)*8);

    // preamble: DMA K(0)
#pragma unroll
    for (int u = 0; u < 3; ++u)
        dma16(Kf + ((size_t)kb16*24 + w*3 + u)*512 + lane*8, &Kb[(w*3+u)*512]);
    __syncthreads();

    f32x4 o_acc[12] = {};   // 48 VGPRs

    for (int t = 0; t < 32; ++t) {
        // ---- ph1(t): 3 heads x 16 keys ----
        f32x4 s3[3];
#pragma unroll
        for (int hh = 0; hh < 3; ++hh) {
            f16x8 ka = *(const f16x8*)(&Kb[(g*6 + hh*2    )*512] + lane*8);
            f16x8 k2 = *(const f16x8*)(&Kb[(g*6 + hh*2 + 1)*512] + lane*8);
            f32x4 a = {};
            a = __builtin_amdgcn_mfma_f32_16x16x32_f16(qreg[hh*2],   ka, a, 0,0,0);
            a = __builtin_amdgcn_mfma_f32_16x16x32_f16(qreg[hh*2+1], k2, a, 0,0,0);
            s3[hh] = a;   // S[q=quad*4+r][k=c]
        }
        // raw scores -> Sr (stride-20 rows: conflict-free b16 writes)
#pragma unroll
        for (int hh = 0; hh < 3; ++hh)
#pragma unroll
            for (int r = 0; r < 4; ++r)
                Sr[(qi*12 + g*3 + hh)*320 + (quad*4 + r)*20 + c] = (_Float16)s3[hh][r];
        // ---- ph2(t-1): 12 heads x d-tile g over 16 keys ----
        if (t > 0) {
#pragma unroll
            for (int h = 0; h < 12; ++h) {
                f16x4 pf = *(const f16x4*)(Pl + (qi*12 + h)*320 + c*20 + quad*4);
                f16x4 vv = *(const f16x4*)(Vb + (h*4 + g)*256 + lane*4);
                o_acc[h] = __builtin_amdgcn_mfma_f32_16x16x16f16(pf, vv, o_acc[h], 0,0,0);
            }
        }
        __syncthreads();   // A: Sr visible; Kb/Vb/Pl free
        // ---- DMA V(t) and K(t+1) (drained at barrier B) ----
#pragma unroll
        for (int u = 0; u < 3; ++u)
            dma16(Vkt + (size_t)(kb16+t)*12288 + (w*3+u)*512 + lane*8,
                  &Vb[(w*3+u)*512]);
        if (t < 31) {
#pragma unroll
            for (int u = 0; u < 3; ++u)
                dma16(Kf + ((size_t)(kb16+t+1)*24 + w*3 + u)*512 + lane*8,
                      &Kb[(w*3+u)*512]);
        }
        // ---- softmax(t): own r = g, all 12 heads, each (q,k,h) once ----
        {
            float e[12];
#pragma unroll
            for (int h = 0; h < 12; ++h)
                e[h] = __expf((float)Sr[(qi*12 + h)*320 + (quad*4 + g)*20 + c]);
            float s01 = e[0]+e[1], s23 = e[2]+e[3], s45 = e[4]+e[5];
            float s67 = e[6]+e[7], s89 = e[8]+e[9], sab = e[10]+e[11];
            float sum = ((s01+s23)+(s45+s67)) + (s89+sab);
            const float inv = 1.0f / (sum * 27.712812921102035f);   // /sqrt(768)
#pragma unroll
            for (int h = 0; h < 12; ++h)
                Pl[(qi*12 + h)*320 + (quad*4 + g)*20 + c] = (_Float16)(e[h]*inv);
        }
        __syncthreads();   // B: P(t) visible; V(t)/K(t+1) arrived
    }
    // ---- tail: ph2(31) ----
#pragma unroll
    for (int h = 0; h < 12; ++h) {
        f16x4 pf = *(const f16x4*)(Pl + (qi*12 + h)*320 + c*20 + quad*4);
        f16x4 vv = *(const f16x4*)(Vb + (h*4 + g)*256 + lane*4);
        o_acc[h] = __builtin_amdgcn_mfma_f32_16x16x16f16(pf, vv, o_acc[h], 0,0,0);
    }

    // ---- epilogue: C[q=quad*4+r][d=c] for d-tile g ----
    if (ks == 0) {
#pragma unroll
        for (int h = 0; h < 12; ++h) {
            const int col = h*64 + g*16 + c;
#pragma unroll
            for (int r = 0; r < 4; ++r)
                out[(size_t)(qrow0 + qi*16 + quad*4 + r) * DIM + col] = o_acc[h][r];
        }
    } else {
        _Float16* dst = part + (size_t)(ks - 1) * ROWS * DIM;
#pragma unroll
        for (int h = 0; h < 12; ++h) {
            const int col = h*64 + g*16 + c;
#pragma unroll
            for (int r = 0; r < 4; ++r)
                dst[(size_t)(qrow0 + qi*16 + quad*4 + r) * DIM + col] =
                    (_Float16)o_acc[h][r];
        }
    }
}

// ---- out += sum of 3 f16 partials ----
__global__ __launch_bounds__(256) void reduce_add4(
    float* __restrict__ out, const _Float16* __restrict__ part, int n4)
{
    int i = blockIdx.x * 256 + threadIdx.x;
    if (i >= n4) return;
    float4 o = reinterpret_cast<float4*>(out)[i];
    const size_t N = (size_t)ROWS * DIM;
#pragma unroll
    for (int p = 0; p < 3; ++p) {
        f16x4 v = reinterpret_cast<const f16x4*>(part + p * N)[i];
        o.x += (float)v[0]; o.y += (float)v[1]; o.z += (float)v[2]; o.w += (float)v[3];
    }
    reinterpret_cast<float4*>(out)[i] = o;
}

// ------------------------------- launch ----------------------------------
extern "C" void kernel_launch(void* const* d_in, const int* in_sizes, int n_in,
                              void* d_out, int out_size, void* d_ws, size_t ws_size,
                              hipStream_t stream)
{
    const float* x  = (const float*)d_in[0];
    const float* Wq = (const float*)d_in[1];
    const float* Wk = (const float*)d_in[2];
    const float* Wv = (const float*)d_in[3];

    _Float16* ws  = (_Float16*)d_ws;
    const size_t XS = (size_t)ROWS * DIM;   // 3145728
    const size_t WS = (size_t)DIM * DIM;    // 589824
    _Float16* xf   = ws;
    _Float16* wqf  = xf  + XS;              // wq+wk adjacent = stacked [Wq;Wk]
    _Float16* wkf  = wqf + WS;
    _Float16* wvf  = wkf + WS;
    _Float16* Qf   = wvf + WS;
    _Float16* Kf   = Qf  + XS;
    _Float16* Vkt  = Kf  + XS;
    _Float16* part = Vkt + XS;              // 3 * XS f16 partials

    cvt_all<<<2400, 256, 0, stream>>>(x, Wq, Wk, Wv, xf, wqf, wkf, wvf);
    gemm3<<<576, 256, 0, stream>>>(xf, wqf, wvf, Qf, Kf, Vkt);
    attn_kernel<<<BATCH * KSPLIT * 64, 512, 0, stream>>>(
        Qf, Kf, Vkt, (float*)d_out, part);
    reduce_add4<<<(int)(XS/4 + 255)/256, 256, 0, stream>>>(
        (float*)d_out, part, (int)(XS/4));
}

// Round 9
// 190.670 us; speedup vs baseline: 1.5446x; 1.0064x over previous
//
#include <hip/hip_runtime.h>

#define DIM 768
#define NHEADS 12
#define HDIM 64
#define BATCH 2
#define SEQ 2048
#define ROWS (BATCH*SEQ)   // 4096
#define KSPLIT 4

typedef __attribute__((ext_vector_type(8))) _Float16 f16x8;
typedef __attribute__((ext_vector_type(4))) _Float16 f16x4;
typedef __attribute__((ext_vector_type(2))) _Float16 f16x2;
typedef __attribute__((ext_vector_type(4))) float    f32x4;

// async global->LDS DMA, 16 B per lane; LDS dest must be wave-uniform base
__device__ __forceinline__ void dma16(const _Float16* g, _Float16* l) {
    __builtin_amdgcn_global_load_lds(
        (const __attribute__((address_space(1))) unsigned int*)g,
        (__attribute__((address_space(3))) unsigned int*)l, 16, 0, 0);
}

// ============================================================
// Fragment layout F(mt, kt): 16 rows x 32 cols of row-major M[R][C]:
//   frag[lane][j] = M[mt*16 + (lane&15)][kt*32 + (lane>>4)*8 + j]
// stored at dst[((mt*(C/32) + kt)*64 + lane)*8] (halves).
// V tile layout (for 16x16x16 PV MFMA): per 16-key chunk kc,
//   Vkt[((kc*48 + (h*4+dt))*64 + lane)*4] : tile[lane][j] =
//   V[d = (h*4+dt)*16 + (lane&15)][key = kc*16 + (lane>>4)*4 + j]
// ============================================================

// ---- all 4 fp32->f16 frag conversions in one launch (all have C=768) ----
__global__ __launch_bounds__(256) void cvt_all(
    const float* __restrict__ x,  const float* __restrict__ wq,
    const float* __restrict__ wk, const float* __restrict__ wv,
    _Float16* __restrict__ xf,  _Float16* __restrict__ wqf,
    _Float16* __restrict__ wkf, _Float16* __restrict__ wvf)
{
    const int lane = threadIdx.x & 63;
    const int wid  = (blockIdx.x * 256 + threadIdx.x) >> 6;
    const float* src; _Float16* dst; int t;
    if (wid < 6144)      { src = x;  dst = xf;  t = wid;        }
    else if (wid < 7296) { src = wq; dst = wqf; t = wid - 6144; }
    else if (wid < 8448) { src = wk; dst = wkf; t = wid - 7296; }
    else                 { src = wv; dst = wvf; t = wid - 8448; }
    const int c = lane & 15, quad = lane >> 4;
    const int mt = t / 24, kt = t % 24;
    const float* p = src + (size_t)(mt*16 + c) * 768 + kt*32 + quad*8;
    float4 v0 = *(const float4*)p;
    float4 v1 = *(const float4*)(p + 4);
    f16x8 o;
    o[0]=(_Float16)v0.x; o[1]=(_Float16)v0.y; o[2]=(_Float16)v0.z; o[3]=(_Float16)v0.w;
    o[4]=(_Float16)v1.x; o[5]=(_Float16)v1.y; o[6]=(_Float16)v1.z; o[7]=(_Float16)v1.w;
    *reinterpret_cast<f16x8*>(dst + ((size_t)t * 64 + lane) * 8) = o;
}

// ---- all 3 projections: 128x128 tiles, global_load_lds staging ----
// bid < 384: C = x * [Wq;Wk]^T  (M=4096, N=1536) -> Qf/Kf frag layout
// bid >= 384: C = Wv * x^T      (M=768, N=4096)  -> Vkt 16x16 tile layout
__global__ __launch_bounds__(256) void gemm3(
    const _Float16* __restrict__ xf, const _Float16* __restrict__ wqkf,
    const _Float16* __restrict__ wvf,
    _Float16* __restrict__ Qf, _Float16* __restrict__ Kf, _Float16* __restrict__ Vkt)
{
    __shared__ _Float16 Ab[2][8*512];
    __shared__ _Float16 Bb[2][8*512];
    const int tid = threadIdx.x, lane = tid & 63, w = tid >> 6;
    const int c = lane & 15, quad = lane >> 4;

    const _Float16 *Af, *Bf;
    int mt0, nt0, mode;
    if ((int)blockIdx.x < 384) {
        int mt = blockIdx.x / 12, nt = blockIdx.x % 12;
        Af = xf; Bf = wqkf; mt0 = mt*8; nt0 = nt*8; mode = 0;
    } else {
        int v = blockIdx.x - 384;
        int mt = v / 32, nt = v % 32;
        Af = wvf; Bf = xf; mt0 = mt*8; nt0 = nt*8; mode = 1;
    }

    auto stage = [&](int kt, int buf) {
#pragma unroll
        for (int u = 0; u < 4; ++u) {
            const int cc = w*4 + u;
            const _Float16* s = (cc < 8) ? Af + ((size_t)(mt0+cc)*24 + kt)*512
                                         : Bf + ((size_t)(nt0+cc-8)*24 + kt)*512;
            _Float16* d = (cc < 8) ? &Ab[buf][cc*512] : &Bb[buf][(cc-8)*512];
            dma16(s + lane*8, d);
        }
    };

    stage(0, 0);
    __syncthreads();

    f32x4 acc[4][4] = {};
    for (int kt = 0; kt < 24; ++kt) {
        const int cur = kt & 1;
        if (kt < 23) stage(kt+1, cur^1);
        f16x8 a[4], b[4];
#pragma unroll
        for (int i = 0; i < 4; ++i)
            a[i] = *(const f16x8*)(&Ab[cur][((w>>1)*4 + i)*512] + lane*8);
#pragma unroll
        for (int j = 0; j < 4; ++j)
            b[j] = *(const f16x8*)(&Bb[cur][((w&1)*4 + j)*512] + lane*8);
#pragma unroll
        for (int i = 0; i < 4; ++i)
#pragma unroll
            for (int j = 0; j < 4; ++j)
                acc[i][j] = __builtin_amdgcn_mfma_f32_16x16x32_f16(a[i], b[j], acc[i][j], 0,0,0);
        __syncthreads();
    }

    // epilogue: per-wave 32x32 transposes (buffers dead after last barrier)
    _Float16* L = &Ab[0][0] + w*1280;   // 32x40 halves per wave
#pragma unroll
    for (int i2 = 0; i2 < 2; ++i2)
#pragma unroll
        for (int j2 = 0; j2 < 2; ++j2) {
#pragma unroll
            for (int ii = 0; ii < 2; ++ii)
#pragma unroll
                for (int jj = 0; jj < 2; ++jj)
#pragma unroll
                    for (int r = 0; r < 4; ++r)
                        L[(ii*16 + quad*4 + r)*40 + jj*16 + c] =
                            (_Float16)acc[i2*2+ii][j2*2+jj][r];
#pragma unroll
            for (int ii = 0; ii < 2; ++ii) {
                const int mtg = mt0 + (w>>1)*4 + i2*2 + ii;   // 16-row unit
                if (mode == 0) {
                    f16x8 v = *(const f16x8*)(L + (ii*16 + c)*40 + quad*8);
                    const int nt32 = (nt0 + (w&1)*4)/2 + j2;  // 32-col unit
                    _Float16* dst = (nt32 < 24)
                        ? Qf + ((size_t)(mtg*24 + nt32)*64 + lane)*8
                        : Kf + ((size_t)(mtg*24 + nt32 - 24)*64 + lane)*8;
                    *(f16x8*)dst = v;
                } else {
#pragma unroll
                    for (int jj = 0; jj < 2; ++jj) {
                        f16x4 v4 = *(const f16x4*)(L + (ii*16 + c)*40 + jj*16 + quad*4);
                        const int kcu = nt0 + (w&1)*4 + j2*2 + jj;   // 16-key unit
                        *(f16x4*)(Vkt + ((size_t)kcu*48 + mtg)*256 + lane*4) = v4;
                    }
                }
            }
        }
}

// ---- fused attention: Tq=64, 1024 thr, 16 waves, 2 barriers/iter ----
// grid: 2b x 4ks x 32qb = 256 blocks (1/CU), 1024 thr (16 waves, 4/SIMD).
// Block = 64 q-rows (4 qt) x 512 keys; 32 subtiles of 16 keys.
// Wave (qi = w>>2, g = w&3):
//   ph1: heads 3g..3g+2 x 16 keys  (qreg 24 + s3 12 VGPRs)
//   softmax: owns r = g (4-way r-split, each (q,k,h) exactly once)
//   ph2: all 12 heads x d-tile dt = g (o_acc 48 AGPRs), lags one subtile.
// DMA duty: waves 0..7 stage K, waves 8..15 stage V (3 chunks each).
// Loop invariant entering iter t: Kb=K(t), Vb=V(t-1), Pl=P(t-1).
//   [ph1(t); s->Sr; ph2(t-1)] barrier A [dma V(t),K(t+1); softmax Sr->Pl] barrier B
__global__ __launch_bounds__(1024) __attribute__((amdgpu_waves_per_eu(4)))
void attn_kernel(
    const _Float16* __restrict__ Qf, const _Float16* __restrict__ Kf,
    const _Float16* __restrict__ Vkt,
    float* __restrict__ out,          // ks==0 partial (covers all elements)
    _Float16* __restrict__ part)      // [3][4096][768] f16, ks=1..3
{
    __shared__ _Float16 Kb[24*512];     // 24 KB: K subtile (24 frags)
    __shared__ _Float16 Vb[48*256];     // 24 KB: V subtile (48 16x16 tiles)
    __shared__ _Float16 Sr[4*12*320];   // 30 KB: raw scores, q-row stride 20
    __shared__ _Float16 Pl[4*12*320];   // 30 KB: P, same layout
    const int tid = threadIdx.x, lane = tid & 63, w = tid >> 6;
    const int c = lane & 15, quad = lane >> 4;
    const int qi = w >> 2, g = w & 3;

    const int bid = blockIdx.x;
    const int qb = bid & 31;
    const int ks = (bid >> 5) & 3;
    const int b  = bid >> 7;
    const int qrow0 = b*SEQ + qb*64;
    const int qt16  = (qrow0 >> 4) + qi;
    const int kb16  = (b*SEQ + ks*(SEQ/KSPLIT)) >> 4;

    // Q frags: q-tile qi, heads 3g..3g+2 (24 VGPRs)
    f16x8 qreg[6];
#pragma unroll
    for (int u = 0; u < 6; ++u)
        qreg[u] = *(const f16x8*)(Qf + ((size_t)(qt16*24 + g*6 + u)*64 + lane)*8);

    // preamble: DMA K(0) (waves 0..7)
    if (w < 8) {
#pragma unroll
        for (int u = 0; u < 3; ++u)
            dma16(Kf + ((size_t)kb16*24 + w*3 + u)*512 + lane*8, &Kb[(w*3+u)*512]);
    }
    __syncthreads();

    f32x4 o_acc[12] = {};   // 48 AGPRs

    for (int t = 0; t < 32; ++t) {
        // ---- ph1(t): 3 heads x 16 keys ----
        f32x4 s3[3];
#pragma unroll
        for (int hh = 0; hh < 3; ++hh) {
            f16x8 ka = *(const f16x8*)(&Kb[(g*6 + hh*2    )*512] + lane*8);
            f16x8 k2 = *(const f16x8*)(&Kb[(g*6 + hh*2 + 1)*512] + lane*8);
            f32x4 a = {};
            a = __builtin_amdgcn_mfma_f32_16x16x32_f16(qreg[hh*2],   ka, a, 0,0,0);
            a = __builtin_amdgcn_mfma_f32_16x16x32_f16(qreg[hh*2+1], k2, a, 0,0,0);
            s3[hh] = a;   // S[q=quad*4+r][k=c]
        }
        // raw scores -> Sr (stride-20 rows: conflict-free b16 writes)
#pragma unroll
        for (int hh = 0; hh < 3; ++hh)
#pragma unroll
            for (int r = 0; r < 4; ++r)
                Sr[(qi*12 + g*3 + hh)*320 + (quad*4 + r)*20 + c] = (_Float16)s3[hh][r];
        // ---- ph2(t-1): 12 heads x d-tile g over 16 keys ----
        if (t > 0) {
#pragma unroll
            for (int h = 0; h < 12; ++h) {
                f16x4 pf = *(const f16x4*)(Pl + (qi*12 + h)*320 + c*20 + quad*4);
                f16x4 vv = *(const f16x4*)(Vb + (h*4 + g)*256 + lane*4);
                o_acc[h] = __builtin_amdgcn_mfma_f32_16x16x16f16(pf, vv, o_acc[h], 0,0,0);
            }
        }
        __syncthreads();   // A: Sr visible; Kb/Vb/Pl free
        // ---- DMA V(t) [waves 8..15] and K(t+1) [waves 0..7] ----
        if (w >= 8) {
#pragma unroll
            for (int u = 0; u < 3; ++u)
                dma16(Vkt + (size_t)(kb16+t)*12288 + ((w-8)*3+u)*512 + lane*8,
                      &Vb[((w-8)*3+u)*512]);
        } else if (t < 31) {
#pragma unroll
            for (int u = 0; u < 3; ++u)
                dma16(Kf + ((size_t)(kb16+t+1)*24 + w*3 + u)*512 + lane*8,
                      &Kb[(w*3+u)*512]);
        }
        // ---- softmax(t): own r = g, all 12 heads, each (q,k,h) once ----
        {
            float e[12];
#pragma unroll
            for (int h = 0; h < 12; ++h)
                e[h] = __expf((float)Sr[(qi*12 + h)*320 + (quad*4 + g)*20 + c]);
            float s01 = e[0]+e[1], s23 = e[2]+e[3], s45 = e[4]+e[5];
            float s67 = e[6]+e[7], s89 = e[8]+e[9], sab = e[10]+e[11];
            float sum = ((s01+s23)+(s45+s67)) + (s89+sab);
            const float inv = 1.0f / (sum * 27.712812921102035f);   // /sqrt(768)
#pragma unroll
            for (int h = 0; h < 12; ++h)
                Pl[(qi*12 + h)*320 + (quad*4 + g)*20 + c] = (_Float16)(e[h]*inv);
        }
        __syncthreads();   // B: P(t) visible; V(t)/K(t+1) arrived
    }
    // ---- tail: ph2(31) ----
#pragma unroll
    for (int h = 0; h < 12; ++h) {
        f16x4 pf = *(const f16x4*)(Pl + (qi*12 + h)*320 + c*20 + quad*4);
        f16x4 vv = *(const f16x4*)(Vb + (h*4 + g)*256 + lane*4);
        o_acc[h] = __builtin_amdgcn_mfma_f32_16x16x16f16(pf, vv, o_acc[h], 0,0,0);
    }

    // ---- epilogue: C[q=quad*4+r][d=c] for d-tile g ----
    if (ks == 0) {
#pragma unroll
        for (int h = 0; h < 12; ++h) {
            const int col = h*64 + g*16 + c;
#pragma unroll
            for (int r = 0; r < 4; ++r)
                out[(size_t)(qrow0 + qi*16 + quad*4 + r) * DIM + col] = o_acc[h][r];
        }
    } else {
        _Float16* dst = part + (size_t)(ks - 1) * ROWS * DIM;
#pragma unroll
        for (int h = 0; h < 12; ++h) {
            const int col = h*64 + g*16 + c;
#pragma unroll
            for (int r = 0; r < 4; ++r)
                dst[(size_t)(qrow0 + qi*16 + quad*4 + r) * DIM + col] =
                    (_Float16)o_acc[h][r];
        }
    }
}

// ---- out += sum of 3 f16 partials ----
__global__ __launch_bounds__(256) void reduce_add4(
    float* __restrict__ out, const _Float16* __restrict__ part, int n4)
{
    int i = blockIdx.x * 256 + threadIdx.x;
    if (i >= n4) return;
    float4 o = reinterpret_cast<float4*>(out)[i];
    const size_t N = (size_t)ROWS * DIM;
#pragma unroll
    for (int p = 0; p < 3; ++p) {
        f16x4 v = reinterpret_cast<const f16x4*>(part + p * N)[i];
        o.x += (float)v[0]; o.y += (float)v[1]; o.z += (float)v[2]; o.w += (float)v[3];
    }
    reinterpret_cast<float4*>(out)[i] = o;
}

// ------------------------------- launch ----------------------------------
extern "C" void kernel_launch(void* const* d_in, const int* in_sizes, int n_in,
                              void* d_out, int out_size, void* d_ws, size_t ws_size,
                              hipStream_t stream)
{
    const float* x  = (const float*)d_in[0];
    const float* Wq = (const float*)d_in[1];
    const float* Wk = (const float*)d_in[2];
    const float* Wv = (const float*)d_in[3];

    _Float16* ws  = (_Float16*)d_ws;
    const size_t XS = (size_t)ROWS * DIM;   // 3145728
    const size_t WS = (size_t)DIM * DIM;    // 589824
    _Float16* xf   = ws;
    _Float16* wqf  = xf  + XS;              // wq+wk adjacent = stacked [Wq;Wk]
    _Float16* wkf  = wqf + WS;
    _Float16* wvf  = wkf + WS;
    _Float16* Qf   = wvf + WS;
    _Float16* Kf   = Qf  + XS;
    _Float16* Vkt  = Kf  + XS;
    _Float16* part = Vkt + XS;              // 3 * XS f16 partials

    cvt_all<<<2400, 256, 0, stream>>>(x, Wq, Wk, Wv, xf, wqf, wkf, wvf);
    gemm3<<<576, 256, 0, stream>>>(xf, wqf, wvf, Qf, Kf, Vkt);
    attn_kernel<<<BATCH * KSPLIT * 32, 1024, 0, stream>>>(
        Qf, Kf, Vkt, (float*)d_out, part);
    reduce_add4<<<(int)(XS/4 + 255)/256, 256, 0, stream>>>(
        (float*)d_out, part, (int)(XS/4));
}